// Round 5
// baseline (580.331 us; speedup 1.0000x reference)
//
#include <hip/hip_runtime.h>
#include <hip/hip_fp16.h>

// GCN 2-layer: 256 -> 16 -> 1, N=100000, E=3.2M + self loops.
//   out[d] = isq[d]*(sum_src ts[src] + ts[d]) + b2,  ts = (h2 @ W2)*isq
//   h2 = relu(isq[d]*(sum_src hs[src] + hs[d]) + b1), hs = (x @ W1)*isq
// R13: SORT ELIMINATED. k_p1 bins edges by super-bucket (256 nodes, dst>>8)
// only; aggregation streams the unsorted region and accumulates into LDS
// with ds_add_f32 (facc[256][16] f32, 16KB, feature slot XOR-swizzled by
// (d>>1)&15 so banks = 16*(d&1) + (f^((d>>1)&15)) cover all 32 uniformly).
// This deletes k_sortsb (25.6MB traffic + LDS sort) and the rowp CSR.
// Degrees for isq come from k_deg (coalesced region read + LDS hist-256).
// R9-12 history: lin1 wave-uniform W1 (s_load) + 2-wave K-split; p1 ITEMS=8
// (391 blocks); gcur padded 64B/entry.

#define SBSH 8              // 256 nodes per super-bucket
#define SBCAP 10240         // region capacity (mean 8192, +22 sigma)
#define HPAD 400            // >= Bsb = ceil(N/256) = 391
#define GSTR 16             // gcur stride in ints (64B line each)
#define BINTHREADS 1024
#define ITEMS 8             // edges per thread in k_p1

__global__ void k_init(int* __restrict__ gcur, int Bsb) {
    int i = blockIdx.x * blockDim.x + threadIdx.x;
    if (i < Bsb) gcur[i * GSTR] = i * SBCAP;
}

// Pass 1: counting scatter into super-bucket regions. Per-block LDS histogram,
// one bulk global claim per super-bucket (~21-int runs at ITEMS=8).
__global__ __launch_bounds__(BINTHREADS) void k_p1(
    const int* __restrict__ src, const int* __restrict__ dst,
    int* __restrict__ gcur, int* __restrict__ pairs, int E, int Bsb)
{
    __shared__ int hist[HPAD];
    const int t = threadIdx.x;
    const int base4 = blockIdx.x * (BINTHREADS * ITEMS / 4);
    for (int i = t; i < HPAD; i += BINTHREADS) hist[i] = 0;
    __syncthreads();

    int4 dd[ITEMS / 4];
    #pragma unroll
    for (int r = 0; r < ITEMS / 4; ++r) {
        const int i4 = base4 + r * BINTHREADS + t;
        const int i = i4 << 2;
        int4 v;
        if (i + 3 < E) v = ((const int4*)dst)[i4];
        else {
            v.x = (i     < E) ? dst[i]     : -1;
            v.y = (i + 1 < E) ? dst[i + 1] : -1;
            v.z = (i + 2 < E) ? dst[i + 2] : -1;
            v.w = (i + 3 < E) ? dst[i + 3] : -1;
        }
        dd[r] = v;
        if (v.x >= 0) atomicAdd(&hist[v.x >> SBSH], 1);
        if (v.y >= 0) atomicAdd(&hist[v.y >> SBSH], 1);
        if (v.z >= 0) atomicAdd(&hist[v.z >> SBSH], 1);
        if (v.w >= 0) atomicAdd(&hist[v.w >> SBSH], 1);
    }
    __syncthreads();
    for (int i = t; i < Bsb; i += BINTHREADS) {
        int c = hist[i];
        hist[i] = c ? atomicAdd(&gcur[i * GSTR], c) : 0;  // bulk claim
    }
    __syncthreads();
    #pragma unroll
    for (int r = 0; r < ITEMS / 4; ++r) {
        const int i4 = base4 + r * BINTHREADS + t;
        const int i = i4 << 2;
        int4 s;
        if (i + 3 < E) s = ((const int4*)src)[i4];
        else {
            s.x = (i     < E) ? src[i]     : 0;
            s.y = (i + 1 < E) ? src[i + 1] : 0;
            s.z = (i + 2 < E) ? src[i + 2] : 0;
            s.w = (i + 3 < E) ? src[i + 3] : 0;
        }
        int4 v = dd[r];
        if (v.x >= 0) { int p = atomicAdd(&hist[v.x >> SBSH], 1); pairs[p] = (s.x << SBSH) | (v.x & 255); }
        if (v.y >= 0) { int p = atomicAdd(&hist[v.y >> SBSH], 1); pairs[p] = (s.y << SBSH) | (v.y & 255); }
        if (v.z >= 0) { int p = atomicAdd(&hist[v.z >> SBSH], 1); pairs[p] = (s.z << SBSH) | (v.z & 255); }
        if (v.w >= 0) { int p = atomicAdd(&hist[v.w >> SBSH], 1); pairs[p] = (s.w << SBSH) | (v.w & 255); }
    }
}

// Degrees -> isq. Block per super-bucket: coalesced int4 region read,
// LDS hist-256 (bank = d&31, random -> ~2-4 way), rsqrt(deg+1).
__global__ __launch_bounds__(1024) void k_deg(
    const int* __restrict__ pairs, const int* __restrict__ gcur,
    float* __restrict__ isq, int N)
{
    __shared__ int hist[256];
    const int t = threadIdx.x, sb = blockIdx.x;
    const int beg = sb * SBCAP;
    const int cnt = gcur[sb * GSTR] - beg;
    if (t < 256) hist[t] = 0;
    __syncthreads();
    const int c4 = cnt >> 2;
    const int4* p4 = (const int4*)(pairs + beg);
    for (int i = t; i < c4; i += 1024) {
        int4 v = p4[i];
        atomicAdd(&hist[v.x & 255], 1);
        atomicAdd(&hist[v.y & 255], 1);
        atomicAdd(&hist[v.z & 255], 1);
        atomicAdd(&hist[v.w & 255], 1);
    }
    for (int i = (c4 << 2) + t; i < cnt; i += 1024)
        atomicAdd(&hist[pairs[beg + i] & 255], 1);
    __syncthreads();
    if (t < 256) {
        const int n = (sb << SBSH) + t;
        if (n < N) isq[n] = rsqrtf((float)(hist[t] + 1));  // +1 self loop
    }
}

// hs16[n][f] = half( dot(x[n,:], W1[:,f]) * isq[n] ).
// 2-way K-split by wave; readfirstlane keeps W1 index wave-uniform -> s_load.
__global__ __launch_bounds__(256) void k_lin1(
    const float* __restrict__ x, const float* __restrict__ W1,
    const float* __restrict__ isq, __half* __restrict__ hs16, int N)
{
    __shared__ float part[128][16];
    const int t = threadIdx.x;
    const int w = t >> 6, lane = t & 63;
    const int hu = __builtin_amdgcn_readfirstlane(w >> 1);   // uniform half
    const int nl = ((w & 1) << 6) + lane;                    // 0..127
    const int n = blockIdx.x * 128 + nl;
    const int nc = (n < N) ? n : (N - 1);                    // clamped row
    const float4* xr = (const float4*)(x + ((size_t)nc << 8) + (hu << 7));
    float acc[16];
    #pragma unroll
    for (int f = 0; f < 16; ++f) acc[f] = 0.f;
    #pragma unroll 1
    for (int kb = 0; kb < 4; ++kb) {
        float4 xa[8];
        #pragma unroll
        for (int u = 0; u < 8; ++u) xa[u] = xr[(kb << 3) + u];   // 8 in flight
        #pragma unroll
        for (int u = 0; u < 8; ++u) {
            const int k4 = (kb << 3) + u;                        // 0..31
            const float4* wr = (const float4*)W1 + (hu << 9) + (k4 << 4);
            const float xv[4] = { xa[u].x, xa[u].y, xa[u].z, xa[u].w };
            #pragma unroll
            for (int j = 0; j < 4; ++j) {
                #pragma unroll
                for (int f4 = 0; f4 < 4; ++f4) {
                    const float4 wv = wr[(j << 2) + f4];         // uniform
                    acc[(f4 << 2) + 0] = fmaf(xv[j], wv.x, acc[(f4 << 2) + 0]);
                    acc[(f4 << 2) + 1] = fmaf(xv[j], wv.y, acc[(f4 << 2) + 1]);
                    acc[(f4 << 2) + 2] = fmaf(xv[j], wv.z, acc[(f4 << 2) + 2]);
                    acc[(f4 << 2) + 3] = fmaf(xv[j], wv.w, acc[(f4 << 2) + 3]);
                }
            }
        }
    }
    if (hu == 1) {                       // upper-half waves stage partials
        #pragma unroll
        for (int f4 = 0; f4 < 4; ++f4) {
            const int fs = (f4 ^ (nl & 3)) << 2;
            *(float4*)&part[nl][fs] =
                make_float4(acc[(f4 << 2) + 0], acc[(f4 << 2) + 1],
                            acc[(f4 << 2) + 2], acc[(f4 << 2) + 3]);
        }
    }
    __syncthreads();
    if (hu == 0 && n < N) {
        #pragma unroll
        for (int f4 = 0; f4 < 4; ++f4) {
            const int fs = (f4 ^ (nl & 3)) << 2;
            float4 p = *(const float4*)&part[nl][fs];
            acc[(f4 << 2) + 0] += p.x;
            acc[(f4 << 2) + 1] += p.y;
            acc[(f4 << 2) + 2] += p.z;
            acc[(f4 << 2) + 3] += p.w;
        }
        const float iq = isq[n];
        __half2* o = (__half2*)&hs16[(size_t)n << 4];
        #pragma unroll
        for (int f2 = 0; f2 < 8; ++f2)
            o[f2] = __floats2half2_rn(acc[2 * f2] * iq, acc[2 * f2 + 1] * iq);
    }
}

// Layer-1 aggregation, sort-free. Block per super-bucket: stream unsorted
// region; per edge gather 32B hs16[src] and ds_add_f32 16 features into
// facc[256][16] (slot f XOR (d>>1)&15 -> 32-bank uniform). Epilogue fuses
// self-loop + isq + b1 + relu + W2 + isq -> ts.
__global__ __launch_bounds__(1024) void k_agg1f(
    const int* __restrict__ pairs, const int* __restrict__ gcur,
    const __half* __restrict__ hs16, const float* __restrict__ isq,
    const float* __restrict__ b1, const float* __restrict__ W2,
    float* __restrict__ ts, int N)
{
    __shared__ float facc[256 * 16];     // 16KB
    const int t = threadIdx.x, sb = blockIdx.x;
    const int beg = sb * SBCAP;
    const int cnt = gcur[sb * GSTR] - beg;
    #pragma unroll
    for (int i = t; i < 4096; i += 1024) facc[i] = 0.f;
    __syncthreads();
    for (int i = t; i < cnt; i += 1024) {
        const int p = pairs[beg + i];
        const int s = p >> SBSH, d = p & 255;
        const int r = (d >> 1) & 15;
        float* fb = &facc[d << 4];
        union { float4 v; __half2 h[4]; } U0, U1;
        const float4* hr = (const float4*)(hs16 + ((size_t)s << 4));
        U0.v = hr[0];
        U1.v = hr[1];
        #pragma unroll
        for (int c = 0; c < 4; ++c) {
            float2 f2 = __half22float2(U0.h[c]);
            atomicAdd(&fb[(2 * c)     ^ r], f2.x);
            atomicAdd(&fb[(2 * c + 1) ^ r], f2.y);
        }
        #pragma unroll
        for (int c = 0; c < 4; ++c) {
            float2 f2 = __half22float2(U1.h[c]);
            atomicAdd(&fb[(8 + 2 * c) ^ r], f2.x);
            atomicAdd(&fb[(9 + 2 * c) ^ r], f2.y);
        }
    }
    __syncthreads();
    if (t < 256) {
        const int n = (sb << SBSH) + t;
        if (n < N) {
            const float iq = isq[n];
            const int r = (t >> 1) & 15;
            const float* fb = &facc[t << 4];
            union { float4 v; __half2 h[4]; } S0, S1;
            const float4* hr = (const float4*)(hs16 + ((size_t)n << 4));
            S0.v = hr[0];
            S1.v = hr[1];
            float acc = 0.f;
            #pragma unroll
            for (int c = 0; c < 4; ++c) {
                float2 sf = __half22float2(S0.h[c]);
                float a0 = fb[(2 * c)     ^ r] + sf.x;      // + self loop
                float a1 = fb[(2 * c + 1) ^ r] + sf.y;
                acc += fmaxf(a0 * iq + b1[2 * c],     0.f) * W2[2 * c]
                     + fmaxf(a1 * iq + b1[2 * c + 1], 0.f) * W2[2 * c + 1];
            }
            #pragma unroll
            for (int c = 0; c < 4; ++c) {
                float2 sf = __half22float2(S1.h[c]);
                float a0 = fb[(8 + 2 * c) ^ r] + sf.x;
                float a1 = fb[(9 + 2 * c) ^ r] + sf.y;
                acc += fmaxf(a0 * iq + b1[8 + 2 * c], 0.f) * W2[8 + 2 * c]
                     + fmaxf(a1 * iq + b1[9 + 2 * c], 0.f) * W2[9 + 2 * c];
            }
            ts[n] = acc * iq;
        }
    }
}

// Layer-2 aggregation, sort-free: sacc[256] f32, one ds_add_f32 per edge
// (bank = d&31, random -> ~2-4 way), scalar ts gather (L2/L3 resident).
__global__ __launch_bounds__(1024) void k_agg2f(
    const int* __restrict__ pairs, const int* __restrict__ gcur,
    const float* __restrict__ ts, const float* __restrict__ isq,
    const float* __restrict__ b2, float* __restrict__ out, int N)
{
    __shared__ float sacc[256];
    const int t = threadIdx.x, sb = blockIdx.x;
    const int beg = sb * SBCAP;
    const int cnt = gcur[sb * GSTR] - beg;
    if (t < 256) sacc[t] = 0.f;
    __syncthreads();
    for (int i = t; i < cnt; i += 1024) {
        const int p = pairs[beg + i];
        atomicAdd(&sacc[p & 255], ts[p >> SBSH]);
    }
    __syncthreads();
    if (t < 256) {
        const int n = (sb << SBSH) + t;
        if (n < N) out[n] = (sacc[t] + ts[n]) * isq[n] + b2[0];
    }
}

extern "C" void kernel_launch(void* const* d_in, const int* in_sizes, int n_in,
                              void* d_out, int out_size, void* d_ws, size_t ws_size,
                              hipStream_t stream) {
    const float* x  = (const float*)d_in[0];
    const int*   ei = (const int*)d_in[1];
    const float* W1 = (const float*)d_in[2];
    const float* b1 = (const float*)d_in[3];
    const float* W2 = (const float*)d_in[4];
    const float* b2 = (const float*)d_in[5];
    const int N = in_sizes[0] / 256;
    const int E = in_sizes[1] / 2;
    const int* src = ei;
    const int* dst = ei + E;
    const int Bsb = (N + 255) >> SBSH;   // 391

    char* w = (char*)d_ws;
    float*  isq   = (float*)w;  w += (size_t)N * 4;
    int*    gcur  = (int*)w;    w += (size_t)HPAD * GSTR * 4;   // padded
    int*    pairs = (int*)w;    w += (size_t)Bsb * SBCAP * 4;   // 16.0 MB
    __half* hs16  = (__half*)w; w += (size_t)N * 32;            // 3.2 MB
    float*  ts    = (float*)w;  w += (size_t)N * 4;
    float*  out   = (float*)d_out;

    k_init<<<(Bsb + 255) / 256, 256, 0, stream>>>(gcur, Bsb);

    const int nbBin = (E + BINTHREADS * ITEMS - 1) / (BINTHREADS * ITEMS);  // 391
    k_p1<<<nbBin, BINTHREADS, 0, stream>>>(src, dst, gcur, pairs, E, Bsb);

    k_deg<<<Bsb, 1024, 0, stream>>>(pairs, gcur, isq, N);

    k_lin1<<<(N + 127) / 128, 256, 0, stream>>>(x, W1, isq, hs16, N);

    k_agg1f<<<Bsb, 1024, 0, stream>>>(pairs, gcur, hs16, isq, b1, W2, ts, N);
    k_agg2f<<<Bsb, 1024, 0, stream>>>(pairs, gcur, ts, isq, b2, out, N);
}